// Round 1
// baseline (1043.524 us; speedup 1.0000x reference)
//
#include <hip/hip_runtime.h>

// GCN encoder: h = relu(A_norm @ (x@W1) + b1); mean = (A_norm@h)@W2+b2; logstd = (A_norm@h)@W3+b3
// A_norm = sym-normalized adjacency with self-loops.
// Plan: build dst-CSR in-kernel once, SpMM = wave-per-node gather (no float atomics),
// aggregation shared between layers 2/3 (scatter commutes with weight GEMM).

#define THREADS 256

// ---------------- zero init (ws is poisoned 0xAA every launch) ----------------
__global__ __launch_bounds__(THREADS) void zero_kernel(float* __restrict__ p, int n) {
    int i = blockIdx.x * THREADS + threadIdx.x;
    if (i < n) p[i] = 0.0f;   // bit pattern 0 also valid for int counts
}

// ---------------- degree + in-degree count histogram ----------------
__global__ __launch_bounds__(THREADS) void deg_count_kernel(
    const int* __restrict__ ei, const float* __restrict__ ew,
    float* __restrict__ deg, int* __restrict__ counts, int E) {
    int e = blockIdx.x * THREADS + threadIdx.x;
    if (e >= E) return;
    int d = ei[E + e];                 // dst row of edge_index
    atomicAdd(&deg[d], ew[e]);
    atomicAdd(&counts[d], 1);
}

// ---------------- exclusive scan over counts + dinv = rsqrt(deg+1) ----------------
__global__ __launch_bounds__(1024) void scan_kernel(
    const int* __restrict__ counts, const float* __restrict__ deg,
    int* __restrict__ offs, int* __restrict__ cursor,
    float* __restrict__ dinvv, int n) {
    __shared__ int s[1024];
    int t = threadIdx.x;
    int per = (n + 1023) >> 10;
    int lo = t * per, hi = min(lo + per, n);
    int sum = 0;
    for (int i = lo; i < hi; ++i) sum += counts[i];
    s[t] = sum;
    __syncthreads();
    // Hillis-Steele inclusive scan of 1024 partials
    for (int off = 1; off < 1024; off <<= 1) {
        int x = (t >= off) ? s[t - off] : 0;
        __syncthreads();
        s[t] += x;
        __syncthreads();
    }
    int run = s[t] - sum;              // exclusive prefix of this thread's range
    for (int i = lo; i < hi; ++i) {
        offs[i] = run;
        cursor[i] = run;
        run += counts[i];
        dinvv[i] = rsqrtf(deg[i] + 1.0f);   // +1 = self-loop weight; deg>=1 always
    }
    if (t == 1023) offs[n] = s[1023];
}

// ---------------- fill CSR (src index + precomputed norm weight) ----------------
__global__ __launch_bounds__(THREADS) void fill_kernel(
    const int* __restrict__ ei, const float* __restrict__ ew,
    const float* __restrict__ dinvv, int* __restrict__ cursor,
    int* __restrict__ csr_src, float* __restrict__ csr_w, int E) {
    int e = blockIdx.x * THREADS + threadIdx.x;
    if (e >= E) return;
    int s = ei[e], d = ei[E + e];
    int pos = atomicAdd(&cursor[d], 1);
    csr_src[pos] = s;
    csr_w[pos] = dinvv[s] * ew[e] * dinvv[d];
}

// ---------------- GEMM1: h0[M,128] = x[M,512] @ W1[512,128], fp32 tiled ----------------
// BM=64, BN=128, BK=16; 256 threads; 4x8 micro-tile per thread.
__global__ __launch_bounds__(THREADS) void gemm1_kernel(
    const float* __restrict__ A, const float* __restrict__ B,
    float* __restrict__ C, int M) {
    __shared__ float As[16][68];    // transposed [k][m], pad 68 -> 2-way-max conflicts
    __shared__ float Bs[16][128];
    int t = threadIdx.x;
    int ty = t >> 4, tx = t & 15;
    int brow0 = blockIdx.x * 64;
    int arow = t >> 2, aq = t & 3;          // A loader: 64 rows x 4 float4
    int bkr = t >> 5, bcol = (t & 31) * 4;  // B loader: 8 rows/pass x 32 float4
    float acc[4][8];
#pragma unroll
    for (int i = 0; i < 4; i++)
#pragma unroll
        for (int j = 0; j < 8; j++) acc[i][j] = 0.0f;
    int gr = brow0 + arow;
    const float4 z4 = make_float4(0.f, 0.f, 0.f, 0.f);
    for (int k0 = 0; k0 < 512; k0 += 16) {
        float4 av = (gr < M) ? *(const float4*)&A[(size_t)gr * 512 + k0 + aq * 4] : z4;
        float4 b0 = *(const float4*)&B[(size_t)(k0 + bkr) * 128 + bcol];
        float4 b1 = *(const float4*)&B[(size_t)(k0 + bkr + 8) * 128 + bcol];
        __syncthreads();
        As[aq * 4 + 0][arow] = av.x;
        As[aq * 4 + 1][arow] = av.y;
        As[aq * 4 + 2][arow] = av.z;
        As[aq * 4 + 3][arow] = av.w;
        *(float4*)&Bs[bkr][bcol] = b0;
        *(float4*)&Bs[bkr + 8][bcol] = b1;
        __syncthreads();
#pragma unroll
        for (int kk = 0; kk < 16; ++kk) {
            float4 a = *(const float4*)&As[kk][ty * 4];
            float4 p0 = *(const float4*)&Bs[kk][tx * 8];
            float4 p1 = *(const float4*)&Bs[kk][tx * 8 + 4];
            float av_[4] = {a.x, a.y, a.z, a.w};
            float bv_[8] = {p0.x, p0.y, p0.z, p0.w, p1.x, p1.y, p1.z, p1.w};
#pragma unroll
            for (int i = 0; i < 4; i++)
#pragma unroll
                for (int j = 0; j < 8; j++)
                    acc[i][j] = fmaf(av_[i], bv_[j], acc[i][j]);
        }
    }
#pragma unroll
    for (int i = 0; i < 4; i++) {
        int r = brow0 + ty * 4 + i;
        if (r < M) {
            *(float4*)&C[(size_t)r * 128 + tx * 8] =
                make_float4(acc[i][0], acc[i][1], acc[i][2], acc[i][3]);
            *(float4*)&C[(size_t)r * 128 + tx * 8 + 4] =
                make_float4(acc[i][4], acc[i][5], acc[i][6], acc[i][7]);
        }
    }
}

// ---------------- SpMM: out[d,:] = sum_e w_e * feat[src_e,:] + dinv[d]^2 * feat[d,:] ----
// one wave per dst node; 2 channels per lane (float2); optional +bias, relu.
__global__ __launch_bounds__(THREADS) void spmm_kernel(
    const float* __restrict__ feat, const float* __restrict__ dinvv,
    const int* __restrict__ offs, const int* __restrict__ csr_src,
    const float* __restrict__ csr_w, const float* __restrict__ bias,
    float* __restrict__ out, int n, int do_relu) {
    int gw = (blockIdx.x * THREADS + threadIdx.x) >> 6;
    int lane = threadIdx.x & 63;
    if (gw >= n) return;
    const int d = gw;
    float di = dinvv[d];
    float sw = di * di;                       // self-loop norm = 1/deg
    float2 acc = *(const float2*)&feat[(size_t)d * 128 + lane * 2];
    acc.x *= sw;
    acc.y *= sw;
    int j = offs[d], end = offs[d + 1];
    for (; j < end; ++j) {
        int s = csr_src[j];                   // wave-uniform
        float w = csr_w[j];                   // wave-uniform
        float2 v = *(const float2*)&feat[(size_t)s * 128 + lane * 2];  // coalesced 512B/row
        acc.x = fmaf(w, v.x, acc.x);
        acc.y = fmaf(w, v.y, acc.y);
    }
    if (bias) {
        float2 b = *(const float2*)&bias[lane * 2];
        acc.x += b.x;
        acc.y += b.y;
    }
    if (do_relu) {
        acc.x = fmaxf(acc.x, 0.0f);
        acc.y = fmaxf(acc.y, 0.0f);
    }
    *(float2*)&out[(size_t)d * 128 + lane * 2] = acc;
}

// ---------------- GEMM23: [mean|logstd] = agg2[M,128] @ [W2|W3][128,128] + [b2|b3] ------
__global__ __launch_bounds__(THREADS) void gemm23_kernel(
    const float* __restrict__ A, const float* __restrict__ W2,
    const float* __restrict__ W3, const float* __restrict__ b2,
    const float* __restrict__ b3, float* __restrict__ outm,
    float* __restrict__ outl, int M) {
    __shared__ float As[16][68];
    __shared__ float Bs[16][128];
    int t = threadIdx.x;
    int ty = t >> 4, tx = t & 15;
    int brow0 = blockIdx.x * 64;
    int arow = t >> 2, aq = t & 3;
    int bkr = t >> 5, bcol = (t & 31) * 4;
    float acc[4][8];
#pragma unroll
    for (int i = 0; i < 4; i++)
#pragma unroll
        for (int j = 0; j < 8; j++) acc[i][j] = 0.0f;
    int gr = brow0 + arow;
    const float4 z4 = make_float4(0.f, 0.f, 0.f, 0.f);
    for (int k0 = 0; k0 < 128; k0 += 16) {
        float4 av = (gr < M) ? *(const float4*)&A[(size_t)gr * 128 + k0 + aq * 4] : z4;
        int k1 = k0 + bkr, k2 = k0 + bkr + 8;
        float4 b0 = (bcol < 64) ? *(const float4*)&W2[(size_t)k1 * 64 + bcol]
                                : *(const float4*)&W3[(size_t)k1 * 64 + bcol - 64];
        float4 b1 = (bcol < 64) ? *(const float4*)&W2[(size_t)k2 * 64 + bcol]
                                : *(const float4*)&W3[(size_t)k2 * 64 + bcol - 64];
        __syncthreads();
        As[aq * 4 + 0][arow] = av.x;
        As[aq * 4 + 1][arow] = av.y;
        As[aq * 4 + 2][arow] = av.z;
        As[aq * 4 + 3][arow] = av.w;
        *(float4*)&Bs[bkr][bcol] = b0;
        *(float4*)&Bs[bkr + 8][bcol] = b1;
        __syncthreads();
#pragma unroll
        for (int kk = 0; kk < 16; ++kk) {
            float4 a = *(const float4*)&As[kk][ty * 4];
            float4 p0 = *(const float4*)&Bs[kk][tx * 8];
            float4 p1 = *(const float4*)&Bs[kk][tx * 8 + 4];
            float av_[4] = {a.x, a.y, a.z, a.w};
            float bv_[8] = {p0.x, p0.y, p0.z, p0.w, p1.x, p1.y, p1.z, p1.w};
#pragma unroll
            for (int i = 0; i < 4; i++)
#pragma unroll
                for (int j = 0; j < 8; j++)
                    acc[i][j] = fmaf(av_[i], bv_[j], acc[i][j]);
        }
    }
    // epilogue: cols 0..63 -> mean (+b2), 64..127 -> logstd (+b3)
    bool is_mean = (tx < 8);
    int c = is_mean ? tx * 8 : tx * 8 - 64;
    const float* bb = is_mean ? b2 : b3;
    float* op = is_mean ? outm : outl;
    float4 bias0 = *(const float4*)&bb[c];
    float4 bias1 = *(const float4*)&bb[c + 4];
#pragma unroll
    for (int i = 0; i < 4; i++) {
        int r = brow0 + ty * 4 + i;
        if (r < M) {
            *(float4*)&op[(size_t)r * 64 + c] =
                make_float4(acc[i][0] + bias0.x, acc[i][1] + bias0.y,
                            acc[i][2] + bias0.z, acc[i][3] + bias0.w);
            *(float4*)&op[(size_t)r * 64 + c + 4] =
                make_float4(acc[i][4] + bias1.x, acc[i][5] + bias1.y,
                            acc[i][6] + bias1.z, acc[i][7] + bias1.w);
        }
    }
}

extern "C" void kernel_launch(void* const* d_in, const int* in_sizes, int n_in,
                              void* d_out, int out_size, void* d_ws, size_t ws_size,
                              hipStream_t stream) {
    const float* x  = (const float*)d_in[0];
    const int*   ei = (const int*)d_in[1];
    const float* ew = (const float*)d_in[2];
    const float* W1 = (const float*)d_in[3];
    const float* b1 = (const float*)d_in[4];
    const float* W2 = (const float*)d_in[5];
    const float* b2 = (const float*)d_in[6];
    const float* W3 = (const float*)d_in[7];
    const float* b3 = (const float*)d_in[8];

    const int n = in_sizes[0] / 512;   // 50000
    const int E = in_sizes[2];         // 1600000

    // workspace carve-up (512B-aligned chunks), ~65 MB total
    char* p = (char*)d_ws;
    auto alloc = [&](size_t bytes) {
        char* q = p;
        p += (bytes + 511) & ~(size_t)511;
        return q;
    };
    float* deg    = (float*)alloc((size_t)2 * n * 4);  // deg + counts contiguous (one zero pass)
    int*   counts = (int*)(deg + n);
    float* dinvv  = (float*)alloc((size_t)n * 4);
    int*   offs   = (int*)alloc((size_t)(n + 1) * 4);
    int*   cursor = (int*)alloc((size_t)n * 4);
    int*   csr_src= (int*)alloc((size_t)E * 4);
    float* csr_w  = (float*)alloc((size_t)E * 4);
    float* h0     = (float*)alloc((size_t)n * 128 * 4);  // xW1, later reused as agg2
    float* hb     = (float*)alloc((size_t)n * 128 * 4);  // relu'd hidden
    float* agg2   = h0;

    float* outm = (float*)d_out;
    float* outl = outm + (size_t)n * 64;

    zero_kernel<<<(2 * n + THREADS - 1) / THREADS, THREADS, 0, stream>>>(deg, 2 * n);
    deg_count_kernel<<<(E + THREADS - 1) / THREADS, THREADS, 0, stream>>>(ei, ew, deg, counts, E);
    scan_kernel<<<1, 1024, 0, stream>>>(counts, deg, offs, cursor, dinvv, n);
    fill_kernel<<<(E + THREADS - 1) / THREADS, THREADS, 0, stream>>>(ei, ew, dinvv, cursor,
                                                                     csr_src, csr_w, E);
    gemm1_kernel<<<(n + 63) / 64, THREADS, 0, stream>>>(x, W1, h0, n);
    spmm_kernel<<<((size_t)n * 64 + THREADS - 1) / THREADS, THREADS, 0, stream>>>(
        h0, dinvv, offs, csr_src, csr_w, b1, hb, n, 1);
    spmm_kernel<<<((size_t)n * 64 + THREADS - 1) / THREADS, THREADS, 0, stream>>>(
        hb, dinvv, offs, csr_src, csr_w, nullptr, agg2, n, 0);
    gemm23_kernel<<<(n + 63) / 64, THREADS, 0, stream>>>(agg2, W2, W3, b2, b3, outm, outl, n);
}

// Round 2
// 863.872 us; speedup vs baseline: 1.2080x; 1.2080x over previous
//
#include <hip/hip_runtime.h>

// GCN encoder: h = relu(A_norm @ (x@W1) + b1); mean = (A_norm@h)@W2+b2; logstd = (A_norm@h)@W3+b3
// A_norm = sym-normalized adjacency with self-loops.
// Plan: build dst-CSR in-kernel once, SpMM = wave-per-node gather (no float atomics),
// aggregation shared between layers 2/3 (scatter commutes with weight GEMM).
// R2: replaced single-block serial scan (195 us, top dispatch in R1 rocprof) with
//     3-stage parallel scan (part1 reduce + dinv, part2 scan partials, part3 local scan).

#define THREADS 256
#define SCAN_CHUNK 2048   // elements per block in the scan kernels (256 thr x 8)

// ---------------- zero init (ws is poisoned 0xAA every launch) ----------------
__global__ __launch_bounds__(THREADS) void zero_kernel(float* __restrict__ p, int n) {
    int i = blockIdx.x * THREADS + threadIdx.x;
    if (i < n) p[i] = 0.0f;   // bit pattern 0 also valid for int counts
}

// ---------------- degree + in-degree count histogram ----------------
__global__ __launch_bounds__(THREADS) void deg_count_kernel(
    const int* __restrict__ ei, const float* __restrict__ ew,
    float* __restrict__ deg, int* __restrict__ counts, int E) {
    int e = blockIdx.x * THREADS + threadIdx.x;
    if (e >= E) return;
    int d = ei[E + e];                 // dst row of edge_index
    atomicAdd(&deg[d], ew[e]);
    atomicAdd(&counts[d], 1);
}

// ---------------- parallel scan stage 1: block sums + dinv ----------------
__global__ __launch_bounds__(THREADS) void scan_part1(
    const int* __restrict__ counts, const float* __restrict__ deg,
    float* __restrict__ dinvv, int* __restrict__ partials, int n) {
    int t = threadIdx.x;
    int base = blockIdx.x * SCAN_CHUNK + t * 8;
    int s = 0;
#pragma unroll
    for (int i = 0; i < 8; ++i) {
        int idx = base + i;
        if (idx < n) {
            s += counts[idx];
            dinvv[idx] = rsqrtf(deg[idx] + 1.0f);  // +1 = self-loop weight
        }
    }
    __shared__ int sm[THREADS];
    sm[t] = s;
    __syncthreads();
    for (int off = THREADS / 2; off > 0; off >>= 1) {
        if (t < off) sm[t] += sm[t + off];
        __syncthreads();
    }
    if (t == 0) partials[blockIdx.x] = sm[0];
}

// ---------------- parallel scan stage 2: exclusive scan of block partials ----------------
__global__ __launch_bounds__(1024) void scan_part2(int* __restrict__ partials, int nb) {
    __shared__ int s[1024];
    int t = threadIdx.x;
    int v = (t < nb) ? partials[t] : 0;
    s[t] = v;
    __syncthreads();
    for (int off = 1; off < 1024; off <<= 1) {
        int x = (t >= off) ? s[t - off] : 0;
        __syncthreads();
        s[t] += x;
        __syncthreads();
    }
    if (t < nb) partials[t] = s[t] - v;   // exclusive prefix
}

// ---------------- parallel scan stage 3: per-block local scan -> offs/cursor ----------------
__global__ __launch_bounds__(THREADS) void scan_part3(
    const int* __restrict__ counts, const int* __restrict__ partials,
    int* __restrict__ offs, int* __restrict__ cursor, int n) {
    int t = threadIdx.x;
    int base = blockIdx.x * SCAN_CHUNK + t * 8;
    int loc[8];
    int s = 0;
#pragma unroll
    for (int i = 0; i < 8; ++i) {
        int idx = base + i;
        int c = (idx < n) ? counts[idx] : 0;
        loc[i] = c;
        s += c;
    }
    __shared__ int sm[THREADS];
    sm[t] = s;
    __syncthreads();
    for (int off = 1; off < THREADS; off <<= 1) {
        int x = (t >= off) ? sm[t - off] : 0;
        __syncthreads();
        sm[t] += x;
        __syncthreads();
    }
    int run = partials[blockIdx.x] + sm[t] - s;   // exclusive prefix of this thread's range
#pragma unroll
    for (int i = 0; i < 8; ++i) {
        int idx = base + i;
        if (idx < n) {
            offs[idx] = run;
            cursor[idx] = run;
            run += loc[i];
            if (idx == n - 1) offs[n] = run;
        }
    }
}

// ---------------- fill CSR (src index + precomputed norm weight) ----------------
__global__ __launch_bounds__(THREADS) void fill_kernel(
    const int* __restrict__ ei, const float* __restrict__ ew,
    const float* __restrict__ dinvv, int* __restrict__ cursor,
    int* __restrict__ csr_src, float* __restrict__ csr_w, int E) {
    int e = blockIdx.x * THREADS + threadIdx.x;
    if (e >= E) return;
    int s = ei[e], d = ei[E + e];
    int pos = atomicAdd(&cursor[d], 1);
    csr_src[pos] = s;
    csr_w[pos] = dinvv[s] * ew[e] * dinvv[d];
}

// ---------------- GEMM1: h0[M,128] = x[M,512] @ W1[512,128], fp32 tiled ----------------
// BM=64, BN=128, BK=16; 256 threads; 4x8 micro-tile per thread.
__global__ __launch_bounds__(THREADS) void gemm1_kernel(
    const float* __restrict__ A, const float* __restrict__ B,
    float* __restrict__ C, int M) {
    __shared__ float As[16][68];    // transposed [k][m], pad 68 -> 2-way-max conflicts
    __shared__ float Bs[16][128];
    int t = threadIdx.x;
    int ty = t >> 4, tx = t & 15;
    int brow0 = blockIdx.x * 64;
    int arow = t >> 2, aq = t & 3;          // A loader: 64 rows x 4 float4
    int bkr = t >> 5, bcol = (t & 31) * 4;  // B loader: 8 rows/pass x 32 float4
    float acc[4][8];
#pragma unroll
    for (int i = 0; i < 4; i++)
#pragma unroll
        for (int j = 0; j < 8; j++) acc[i][j] = 0.0f;
    int gr = brow0 + arow;
    const float4 z4 = make_float4(0.f, 0.f, 0.f, 0.f);
    for (int k0 = 0; k0 < 512; k0 += 16) {
        float4 av = (gr < M) ? *(const float4*)&A[(size_t)gr * 512 + k0 + aq * 4] : z4;
        float4 b0 = *(const float4*)&B[(size_t)(k0 + bkr) * 128 + bcol];
        float4 b1 = *(const float4*)&B[(size_t)(k0 + bkr + 8) * 128 + bcol];
        __syncthreads();
        As[aq * 4 + 0][arow] = av.x;
        As[aq * 4 + 1][arow] = av.y;
        As[aq * 4 + 2][arow] = av.z;
        As[aq * 4 + 3][arow] = av.w;
        *(float4*)&Bs[bkr][bcol] = b0;
        *(float4*)&Bs[bkr + 8][bcol] = b1;
        __syncthreads();
#pragma unroll
        for (int kk = 0; kk < 16; ++kk) {
            float4 a = *(const float4*)&As[kk][ty * 4];
            float4 p0 = *(const float4*)&Bs[kk][tx * 8];
            float4 p1 = *(const float4*)&Bs[kk][tx * 8 + 4];
            float av_[4] = {a.x, a.y, a.z, a.w};
            float bv_[8] = {p0.x, p0.y, p0.z, p0.w, p1.x, p1.y, p1.z, p1.w};
#pragma unroll
            for (int i = 0; i < 4; i++)
#pragma unroll
                for (int j = 0; j < 8; j++)
                    acc[i][j] = fmaf(av_[i], bv_[j], acc[i][j]);
        }
    }
#pragma unroll
    for (int i = 0; i < 4; i++) {
        int r = brow0 + ty * 4 + i;
        if (r < M) {
            *(float4*)&C[(size_t)r * 128 + tx * 8] =
                make_float4(acc[i][0], acc[i][1], acc[i][2], acc[i][3]);
            *(float4*)&C[(size_t)r * 128 + tx * 8 + 4] =
                make_float4(acc[i][4], acc[i][5], acc[i][6], acc[i][7]);
        }
    }
}

// ---------------- SpMM: out[d,:] = sum_e w_e * feat[src_e,:] + dinv[d]^2 * feat[d,:] ----
// one wave per dst node; 2 channels per lane (float2); optional +bias, relu.
__global__ __launch_bounds__(THREADS) void spmm_kernel(
    const float* __restrict__ feat, const float* __restrict__ dinvv,
    const int* __restrict__ offs, const int* __restrict__ csr_src,
    const float* __restrict__ csr_w, const float* __restrict__ bias,
    float* __restrict__ out, int n, int do_relu) {
    int gw = (blockIdx.x * THREADS + threadIdx.x) >> 6;
    int lane = threadIdx.x & 63;
    if (gw >= n) return;
    const int d = gw;
    float di = dinvv[d];
    float sw = di * di;                       // self-loop norm = 1/deg
    float2 acc = *(const float2*)&feat[(size_t)d * 128 + lane * 2];
    acc.x *= sw;
    acc.y *= sw;
    int j = offs[d], end = offs[d + 1];
    for (; j < end; ++j) {
        int s = csr_src[j];                   // wave-uniform
        float w = csr_w[j];                   // wave-uniform
        float2 v = *(const float2*)&feat[(size_t)s * 128 + lane * 2];  // coalesced 512B/row
        acc.x = fmaf(w, v.x, acc.x);
        acc.y = fmaf(w, v.y, acc.y);
    }
    if (bias) {
        float2 b = *(const float2*)&bias[lane * 2];
        acc.x += b.x;
        acc.y += b.y;
    }
    if (do_relu) {
        acc.x = fmaxf(acc.x, 0.0f);
        acc.y = fmaxf(acc.y, 0.0f);
    }
    *(float2*)&out[(size_t)d * 128 + lane * 2] = acc;
}

// ---------------- GEMM23: [mean|logstd] = agg2[M,128] @ [W2|W3][128,128] + [b2|b3] ------
__global__ __launch_bounds__(THREADS) void gemm23_kernel(
    const float* __restrict__ A, const float* __restrict__ W2,
    const float* __restrict__ W3, const float* __restrict__ b2,
    const float* __restrict__ b3, float* __restrict__ outm,
    float* __restrict__ outl, int M) {
    __shared__ float As[16][68];
    __shared__ float Bs[16][128];
    int t = threadIdx.x;
    int ty = t >> 4, tx = t & 15;
    int brow0 = blockIdx.x * 64;
    int arow = t >> 2, aq = t & 3;
    int bkr = t >> 5, bcol = (t & 31) * 4;
    float acc[4][8];
#pragma unroll
    for (int i = 0; i < 4; i++)
#pragma unroll
        for (int j = 0; j < 8; j++) acc[i][j] = 0.0f;
    int gr = brow0 + arow;
    const float4 z4 = make_float4(0.f, 0.f, 0.f, 0.f);
    for (int k0 = 0; k0 < 128; k0 += 16) {
        float4 av = (gr < M) ? *(const float4*)&A[(size_t)gr * 128 + k0 + aq * 4] : z4;
        int k1 = k0 + bkr, k2 = k0 + bkr + 8;
        float4 b0 = (bcol < 64) ? *(const float4*)&W2[(size_t)k1 * 64 + bcol]
                                : *(const float4*)&W3[(size_t)k1 * 64 + bcol - 64];
        float4 b1 = (bcol < 64) ? *(const float4*)&W2[(size_t)k2 * 64 + bcol]
                                : *(const float4*)&W3[(size_t)k2 * 64 + bcol - 64];
        __syncthreads();
        As[aq * 4 + 0][arow] = av.x;
        As[aq * 4 + 1][arow] = av.y;
        As[aq * 4 + 2][arow] = av.z;
        As[aq * 4 + 3][arow] = av.w;
        *(float4*)&Bs[bkr][bcol] = b0;
        *(float4*)&Bs[bkr + 8][bcol] = b1;
        __syncthreads();
#pragma unroll
        for (int kk = 0; kk < 16; ++kk) {
            float4 a = *(const float4*)&As[kk][ty * 4];
            float4 p0 = *(const float4*)&Bs[kk][tx * 8];
            float4 p1 = *(const float4*)&Bs[kk][tx * 8 + 4];
            float av_[4] = {a.x, a.y, a.z, a.w};
            float bv_[8] = {p0.x, p0.y, p0.z, p0.w, p1.x, p1.y, p1.z, p1.w};
#pragma unroll
            for (int i = 0; i < 4; i++)
#pragma unroll
                for (int j = 0; j < 8; j++)
                    acc[i][j] = fmaf(av_[i], bv_[j], acc[i][j]);
        }
    }
    // epilogue: cols 0..63 -> mean (+b2), 64..127 -> logstd (+b3)
    bool is_mean = (tx < 8);
    int c = is_mean ? tx * 8 : tx * 8 - 64;
    const float* bb = is_mean ? b2 : b3;
    float* op = is_mean ? outm : outl;
    float4 bias0 = *(const float4*)&bb[c];
    float4 bias1 = *(const float4*)&bb[c + 4];
#pragma unroll
    for (int i = 0; i < 4; i++) {
        int r = brow0 + ty * 4 + i;
        if (r < M) {
            *(float4*)&op[(size_t)r * 64 + c] =
                make_float4(acc[i][0] + bias0.x, acc[i][1] + bias0.y,
                            acc[i][2] + bias0.z, acc[i][3] + bias0.w);
            *(float4*)&op[(size_t)r * 64 + c + 4] =
                make_float4(acc[i][4] + bias1.x, acc[i][5] + bias1.y,
                            acc[i][6] + bias1.z, acc[i][7] + bias1.w);
        }
    }
}

extern "C" void kernel_launch(void* const* d_in, const int* in_sizes, int n_in,
                              void* d_out, int out_size, void* d_ws, size_t ws_size,
                              hipStream_t stream) {
    const float* x  = (const float*)d_in[0];
    const int*   ei = (const int*)d_in[1];
    const float* ew = (const float*)d_in[2];
    const float* W1 = (const float*)d_in[3];
    const float* b1 = (const float*)d_in[4];
    const float* W2 = (const float*)d_in[5];
    const float* b2 = (const float*)d_in[6];
    const float* W3 = (const float*)d_in[7];
    const float* b3 = (const float*)d_in[8];

    const int n = in_sizes[0] / 512;   // 50000
    const int E = in_sizes[2];         // 1600000
    const int nb_scan = (n + SCAN_CHUNK - 1) / SCAN_CHUNK;   // 25

    // workspace carve-up (512B-aligned chunks), ~65 MB total
    char* p = (char*)d_ws;
    auto alloc = [&](size_t bytes) {
        char* q = p;
        p += (bytes + 511) & ~(size_t)511;
        return q;
    };
    float* deg    = (float*)alloc((size_t)2 * n * 4);  // deg + counts contiguous (one zero pass)
    int*   counts = (int*)(deg + n);
    float* dinvv  = (float*)alloc((size_t)n * 4);
    int*   offs   = (int*)alloc((size_t)(n + 1) * 4);
    int*   cursor = (int*)alloc((size_t)n * 4);
    int*   partials = (int*)alloc((size_t)nb_scan * 4);
    int*   csr_src= (int*)alloc((size_t)E * 4);
    float* csr_w  = (float*)alloc((size_t)E * 4);
    float* h0     = (float*)alloc((size_t)n * 128 * 4);  // xW1, later reused as agg2
    float* hb     = (float*)alloc((size_t)n * 128 * 4);  // relu'd hidden
    float* agg2   = h0;

    float* outm = (float*)d_out;
    float* outl = outm + (size_t)n * 64;

    zero_kernel<<<(2 * n + THREADS - 1) / THREADS, THREADS, 0, stream>>>(deg, 2 * n);
    deg_count_kernel<<<(E + THREADS - 1) / THREADS, THREADS, 0, stream>>>(ei, ew, deg, counts, E);
    scan_part1<<<nb_scan, THREADS, 0, stream>>>(counts, deg, dinvv, partials, n);
    scan_part2<<<1, 1024, 0, stream>>>(partials, nb_scan);
    scan_part3<<<nb_scan, THREADS, 0, stream>>>(counts, partials, offs, cursor, n);
    fill_kernel<<<(E + THREADS - 1) / THREADS, THREADS, 0, stream>>>(ei, ew, dinvv, cursor,
                                                                     csr_src, csr_w, E);
    gemm1_kernel<<<(n + 63) / 64, THREADS, 0, stream>>>(x, W1, h0, n);
    spmm_kernel<<<((size_t)n * 64 + THREADS - 1) / THREADS, THREADS, 0, stream>>>(
        h0, dinvv, offs, csr_src, csr_w, b1, hb, n, 1);
    spmm_kernel<<<((size_t)n * 64 + THREADS - 1) / THREADS, THREADS, 0, stream>>>(
        hb, dinvv, offs, csr_src, csr_w, nullptr, agg2, n, 0);
    gemm23_kernel<<<(n + 63) / 64, THREADS, 0, stream>>>(agg2, W2, W3, b2, b3, outm, outl, n);
}

// Round 4
// 728.802 us; speedup vs baseline: 1.4318x; 1.1853x over previous
//
#include <hip/hip_runtime.h>

// GCN encoder: h = relu(A_norm @ (x@W1) + b1); mean = (A_norm@h)@W2+b2; logstd = (A_norm@h)@W3+b3
// A_norm = sym-normalized adjacency with self-loops.
// Plan: build dst-CSR in-kernel once, SpMM = wave-per-node gather (no float atomics),
// aggregation shared between layers 2/3 (scatter commutes with weight GEMM).
// R2: 3-stage parallel scan (was 195us serial -> ~10us).
// R3: spmm was latency-bound (VALUBusy 14%, HBM 30%): packed int2 CSR, scalar (readfirstlane)
//     csr path on lgkmcnt, explicit ping-pong software pipeline with 2 feat-groups in flight.
// R4: resubmit of R3 (previous bench never ran: GPU acquisition timeout).

#define THREADS 256
#define SCAN_CHUNK 2048   // elements per block in the scan kernels (256 thr x 8)
#define D 4               // spmm pipeline group size (2 groups in flight = 8 feat loads)

// ---------------- zero init (ws is poisoned 0xAA every launch) ----------------
__global__ __launch_bounds__(THREADS) void zero_kernel(float* __restrict__ p, int n) {
    int i = blockIdx.x * THREADS + threadIdx.x;
    if (i < n) p[i] = 0.0f;   // bit pattern 0 also valid for int counts
}

// ---------------- degree + in-degree count histogram ----------------
__global__ __launch_bounds__(THREADS) void deg_count_kernel(
    const int* __restrict__ ei, const float* __restrict__ ew,
    float* __restrict__ deg, int* __restrict__ counts, int E) {
    int e = blockIdx.x * THREADS + threadIdx.x;
    if (e >= E) return;
    int d = ei[E + e];                 // dst row of edge_index
    atomicAdd(&deg[d], ew[e]);
    atomicAdd(&counts[d], 1);
}

// ---------------- parallel scan stage 1: block sums + dinv ----------------
__global__ __launch_bounds__(THREADS) void scan_part1(
    const int* __restrict__ counts, const float* __restrict__ deg,
    float* __restrict__ dinvv, int* __restrict__ partials, int n) {
    int t = threadIdx.x;
    int base = blockIdx.x * SCAN_CHUNK + t * 8;
    int s = 0;
#pragma unroll
    for (int i = 0; i < 8; ++i) {
        int idx = base + i;
        if (idx < n) {
            s += counts[idx];
            dinvv[idx] = rsqrtf(deg[idx] + 1.0f);  // +1 = self-loop weight
        }
    }
    __shared__ int sm[THREADS];
    sm[t] = s;
    __syncthreads();
    for (int off = THREADS / 2; off > 0; off >>= 1) {
        if (t < off) sm[t] += sm[t + off];
        __syncthreads();
    }
    if (t == 0) partials[blockIdx.x] = sm[0];
}

// ---------------- parallel scan stage 2: exclusive scan of block partials ----------------
__global__ __launch_bounds__(1024) void scan_part2(int* __restrict__ partials, int nb) {
    __shared__ int s[1024];
    int t = threadIdx.x;
    int v = (t < nb) ? partials[t] : 0;
    s[t] = v;
    __syncthreads();
    for (int off = 1; off < 1024; off <<= 1) {
        int x = (t >= off) ? s[t - off] : 0;
        __syncthreads();
        s[t] += x;
        __syncthreads();
    }
    if (t < nb) partials[t] = s[t] - v;   // exclusive prefix
}

// ---------------- parallel scan stage 3: per-block local scan -> offs/cursor ----------------
__global__ __launch_bounds__(THREADS) void scan_part3(
    const int* __restrict__ counts, const int* __restrict__ partials,
    int* __restrict__ offs, int* __restrict__ cursor, int n) {
    int t = threadIdx.x;
    int base = blockIdx.x * SCAN_CHUNK + t * 8;
    int loc[8];
    int s = 0;
#pragma unroll
    for (int i = 0; i < 8; ++i) {
        int idx = base + i;
        int c = (idx < n) ? counts[idx] : 0;
        loc[i] = c;
        s += c;
    }
    __shared__ int sm[THREADS];
    sm[t] = s;
    __syncthreads();
    for (int off = 1; off < THREADS; off <<= 1) {
        int x = (t >= off) ? sm[t - off] : 0;
        __syncthreads();
        sm[t] += x;
        __syncthreads();
    }
    int run = partials[blockIdx.x] + sm[t] - s;   // exclusive prefix of this thread's range
#pragma unroll
    for (int i = 0; i < 8; ++i) {
        int idx = base + i;
        if (idx < n) {
            offs[idx] = run;
            cursor[idx] = run;
            run += loc[i];
            if (idx == n - 1) offs[n] = run;
        }
    }
}

// ---------------- fill CSR (packed: src index + norm weight as int2) ----------------
__global__ __launch_bounds__(THREADS) void fill_kernel(
    const int* __restrict__ ei, const float* __restrict__ ew,
    const float* __restrict__ dinvv, int* __restrict__ cursor,
    int2* __restrict__ csr, int E) {
    int e = blockIdx.x * THREADS + threadIdx.x;
    if (e >= E) return;
    int s = ei[e], d = ei[E + e];
    int pos = atomicAdd(&cursor[d], 1);
    csr[pos] = make_int2(s, __float_as_int(dinvv[s] * ew[e] * dinvv[d]));
}

// ---------------- GEMM1: h0[M,128] = x[M,512] @ W1[512,128], fp32 tiled ----------------
// BM=64, BN=128, BK=16; 256 threads; 4x8 micro-tile per thread.
__global__ __launch_bounds__(THREADS) void gemm1_kernel(
    const float* __restrict__ A, const float* __restrict__ B,
    float* __restrict__ C, int M) {
    __shared__ float As[16][68];    // transposed [k][m], pad 68 -> 2-way-max conflicts
    __shared__ float Bs[16][128];
    int t = threadIdx.x;
    int ty = t >> 4, tx = t & 15;
    int brow0 = blockIdx.x * 64;
    int arow = t >> 2, aq = t & 3;          // A loader: 64 rows x 4 float4
    int bkr = t >> 5, bcol = (t & 31) * 4;  // B loader: 8 rows/pass x 32 float4
    float acc[4][8];
#pragma unroll
    for (int i = 0; i < 4; i++)
#pragma unroll
        for (int j = 0; j < 8; j++) acc[i][j] = 0.0f;
    int gr = brow0 + arow;
    const float4 z4 = make_float4(0.f, 0.f, 0.f, 0.f);
    for (int k0 = 0; k0 < 512; k0 += 16) {
        float4 av = (gr < M) ? *(const float4*)&A[(size_t)gr * 512 + k0 + aq * 4] : z4;
        float4 b0 = *(const float4*)&B[(size_t)(k0 + bkr) * 128 + bcol];
        float4 b1 = *(const float4*)&B[(size_t)(k0 + bkr + 8) * 128 + bcol];
        __syncthreads();
        As[aq * 4 + 0][arow] = av.x;
        As[aq * 4 + 1][arow] = av.y;
        As[aq * 4 + 2][arow] = av.z;
        As[aq * 4 + 3][arow] = av.w;
        *(float4*)&Bs[bkr][bcol] = b0;
        *(float4*)&Bs[bkr + 8][bcol] = b1;
        __syncthreads();
#pragma unroll
        for (int kk = 0; kk < 16; ++kk) {
            float4 a = *(const float4*)&As[kk][ty * 4];
            float4 p0 = *(const float4*)&Bs[kk][tx * 8];
            float4 p1 = *(const float4*)&Bs[kk][tx * 8 + 4];
            float av_[4] = {a.x, a.y, a.z, a.w};
            float bv_[8] = {p0.x, p0.y, p0.z, p0.w, p1.x, p1.y, p1.z, p1.w};
#pragma unroll
            for (int i = 0; i < 4; i++)
#pragma unroll
                for (int j = 0; j < 8; j++)
                    acc[i][j] = fmaf(av_[i], bv_[j], acc[i][j]);
        }
    }
#pragma unroll
    for (int i = 0; i < 4; i++) {
        int r = brow0 + ty * 4 + i;
        if (r < M) {
            *(float4*)&C[(size_t)r * 128 + tx * 8] =
                make_float4(acc[i][0], acc[i][1], acc[i][2], acc[i][3]);
            *(float4*)&C[(size_t)r * 128 + tx * 8 + 4] =
                make_float4(acc[i][4], acc[i][5], acc[i][6], acc[i][7]);
        }
    }
}

// ---------------- SpMM: out[d,:] = sum_e w_e * feat[src_e,:] + dinv[d]^2 * feat[d,:] ----
// one wave per dst node; 2 channels per lane (float2); software-pipelined gather:
//   csr loads are scalar (readfirstlane'd dst -> uniform addr -> s_load, lgkmcnt)
//   feat loads ping-pong, 2 groups of D in flight on vmcnt.
__global__ __launch_bounds__(THREADS) void spmm_kernel(
    const float* __restrict__ feat, const float* __restrict__ dinvv,
    const int* __restrict__ offs, const int2* __restrict__ csr,
    const float* __restrict__ bias, float* __restrict__ out, int n, int do_relu) {
    int gw = (blockIdx.x * THREADS + threadIdx.x) >> 6;
    int lane = threadIdx.x & 63;
    if (gw >= n) return;
    const int d = __builtin_amdgcn_readfirstlane(gw);   // wave-uniform -> SALU/s_load path
    float di = dinvv[d];
    float sw = di * di;                       // self-loop norm = 1/deg
    const float2* __restrict__ f2 = (const float2*)feat + lane;   // f2[64*row]
    float2 acc = f2[(size_t)d * 64];
    acc.x *= sw;
    acc.y *= sw;
    int j0 = offs[d];
    int m = offs[d + 1] - j0;
    const int2* __restrict__ cp = csr + j0;

    int2 eA[D], eB[D];
    float wA[D], wB[D];
    float2 vA[D], vB[D];

    // prologue: csr groups 0 and 1; feat group 0 in flight
#pragma unroll
    for (int i = 0; i < D; ++i) if (i < m) eA[i] = cp[i];
#pragma unroll
    for (int i = 0; i < D; ++i) if (D + i < m) eB[i] = cp[D + i];
#pragma unroll
    for (int i = 0; i < D; ++i) if (i < m) {
        wA[i] = __int_as_float(eA[i].y);
        vA[i] = f2[(size_t)eA[i].x * 64];
    }

    int g = 0;
    for (; g + 4 * D <= m; g += 2 * D) {
        // half 1: consume group g (vA/wA); eB holds csr(g+D)
#pragma unroll
        for (int i = 0; i < D; ++i) eA[i] = cp[g + 2 * D + i];       // csr for g+2D
#pragma unroll
        for (int i = 0; i < D; ++i) {
            wB[i] = __int_as_float(eB[i].y);
            vB[i] = f2[(size_t)eB[i].x * 64];                        // feat for g+D
        }
#pragma unroll
        for (int i = 0; i < D; ++i) {
            acc.x = fmaf(wA[i], vA[i].x, acc.x);
            acc.y = fmaf(wA[i], vA[i].y, acc.y);
        }
        // half 2: consume group g+D (vB/wB); eA holds csr(g+2D)
#pragma unroll
        for (int i = 0; i < D; ++i) eB[i] = cp[g + 3 * D + i];       // csr for g+3D
#pragma unroll
        for (int i = 0; i < D; ++i) {
            wA[i] = __int_as_float(eA[i].y);
            vA[i] = f2[(size_t)eA[i].x * 64];                        // feat for g+2D
        }
#pragma unroll
        for (int i = 0; i < D; ++i) {
            acc.x = fmaf(wB[i], vB[i].x, acc.x);
            acc.y = fmaf(wB[i], vB[i].y, acc.y);
        }
    }
    // epilogue: group g in flight (vA), csr for group g+D resident in eB (guarded)
#pragma unroll
    for (int i = 0; i < D; ++i) if (g + i < m) {
        acc.x = fmaf(wA[i], vA[i].x, acc.x);
        acc.y = fmaf(wA[i], vA[i].y, acc.y);
    }
    g += D;
#pragma unroll
    for (int i = 0; i < D; ++i) if (g + i < m) {
        float w = __int_as_float(eB[i].y);
        float2 v = f2[(size_t)eB[i].x * 64];
        acc.x = fmaf(w, v.x, acc.x);
        acc.y = fmaf(w, v.y, acc.y);
    }
    g += D;
    for (; g < m; ++g) {
        int2 e = cp[g];
        float w = __int_as_float(e.y);
        float2 v = f2[(size_t)e.x * 64];
        acc.x = fmaf(w, v.x, acc.x);
        acc.y = fmaf(w, v.y, acc.y);
    }

    if (bias) {
        float2 b = *(const float2*)&bias[lane * 2];
        acc.x += b.x;
        acc.y += b.y;
    }
    if (do_relu) {
        acc.x = fmaxf(acc.x, 0.0f);
        acc.y = fmaxf(acc.y, 0.0f);
    }
    ((float2*)out)[(size_t)d * 64 + lane] = acc;
}

// ---------------- GEMM23: [mean|logstd] = agg2[M,128] @ [W2|W3][128,128] + [b2|b3] ------
__global__ __launch_bounds__(THREADS) void gemm23_kernel(
    const float* __restrict__ A, const float* __restrict__ W2,
    const float* __restrict__ W3, const float* __restrict__ b2,
    const float* __restrict__ b3, float* __restrict__ outm,
    float* __restrict__ outl, int M) {
    __shared__ float As[16][68];
    __shared__ float Bs[16][128];
    int t = threadIdx.x;
    int ty = t >> 4, tx = t & 15;
    int brow0 = blockIdx.x * 64;
    int arow = t >> 2, aq = t & 3;
    int bkr = t >> 5, bcol = (t & 31) * 4;
    float acc[4][8];
#pragma unroll
    for (int i = 0; i < 4; i++)
#pragma unroll
        for (int j = 0; j < 8; j++) acc[i][j] = 0.0f;
    int gr = brow0 + arow;
    const float4 z4 = make_float4(0.f, 0.f, 0.f, 0.f);
    for (int k0 = 0; k0 < 128; k0 += 16) {
        float4 av = (gr < M) ? *(const float4*)&A[(size_t)gr * 128 + k0 + aq * 4] : z4;
        int k1 = k0 + bkr, k2 = k0 + bkr + 8;
        float4 b0 = (bcol < 64) ? *(const float4*)&W2[(size_t)k1 * 64 + bcol]
                                : *(const float4*)&W3[(size_t)k1 * 64 + bcol - 64];
        float4 b1 = (bcol < 64) ? *(const float4*)&W2[(size_t)k2 * 64 + bcol]
                                : *(const float4*)&W3[(size_t)k2 * 64 + bcol - 64];
        __syncthreads();
        As[aq * 4 + 0][arow] = av.x;
        As[aq * 4 + 1][arow] = av.y;
        As[aq * 4 + 2][arow] = av.z;
        As[aq * 4 + 3][arow] = av.w;
        *(float4*)&Bs[bkr][bcol] = b0;
        *(float4*)&Bs[bkr + 8][bcol] = b1;
        __syncthreads();
#pragma unroll
        for (int kk = 0; kk < 16; ++kk) {
            float4 a = *(const float4*)&As[kk][ty * 4];
            float4 p0 = *(const float4*)&Bs[kk][tx * 8];
            float4 p1 = *(const float4*)&Bs[kk][tx * 8 + 4];
            float av_[4] = {a.x, a.y, a.z, a.w};
            float bv_[8] = {p0.x, p0.y, p0.z, p0.w, p1.x, p1.y, p1.z, p1.w};
#pragma unroll
            for (int i = 0; i < 4; i++)
#pragma unroll
                for (int j = 0; j < 8; j++)
                    acc[i][j] = fmaf(av_[i], bv_[j], acc[i][j]);
        }
    }
    // epilogue: cols 0..63 -> mean (+b2), 64..127 -> logstd (+b3)
    bool is_mean = (tx < 8);
    int c = is_mean ? tx * 8 : tx * 8 - 64;
    const float* bb = is_mean ? b2 : b3;
    float* op = is_mean ? outm : outl;
    float4 bias0 = *(const float4*)&bb[c];
    float4 bias1 = *(const float4*)&bb[c + 4];
#pragma unroll
    for (int i = 0; i < 4; i++) {
        int r = brow0 + ty * 4 + i;
        if (r < M) {
            *(float4*)&op[(size_t)r * 64 + c] =
                make_float4(acc[i][0] + bias0.x, acc[i][1] + bias0.y,
                            acc[i][2] + bias0.z, acc[i][3] + bias0.w);
            *(float4*)&op[(size_t)r * 64 + c + 4] =
                make_float4(acc[i][4] + bias1.x, acc[i][5] + bias1.y,
                            acc[i][6] + bias1.z, acc[i][7] + bias1.w);
        }
    }
}

extern "C" void kernel_launch(void* const* d_in, const int* in_sizes, int n_in,
                              void* d_out, int out_size, void* d_ws, size_t ws_size,
                              hipStream_t stream) {
    const float* x  = (const float*)d_in[0];
    const int*   ei = (const int*)d_in[1];
    const float* ew = (const float*)d_in[2];
    const float* W1 = (const float*)d_in[3];
    const float* b1 = (const float*)d_in[4];
    const float* W2 = (const float*)d_in[5];
    const float* b2 = (const float*)d_in[6];
    const float* W3 = (const float*)d_in[7];
    const float* b3 = (const float*)d_in[8];

    const int n = in_sizes[0] / 512;   // 50000
    const int E = in_sizes[2];         // 1600000
    const int nb_scan = (n + SCAN_CHUNK - 1) / SCAN_CHUNK;   // 25

    // workspace carve-up (512B-aligned chunks), ~65 MB total
    char* p = (char*)d_ws;
    auto alloc = [&](size_t bytes) {
        char* q = p;
        p += (bytes + 511) & ~(size_t)511;
        return q;
    };
    float* deg    = (float*)alloc((size_t)2 * n * 4);  // deg + counts contiguous (one zero pass)
    int*   counts = (int*)(deg + n);
    float* dinvv  = (float*)alloc((size_t)n * 4);
    int*   offs   = (int*)alloc((size_t)(n + 1) * 4);
    int*   cursor = (int*)alloc((size_t)n * 4);
    int*   partials = (int*)alloc((size_t)nb_scan * 4);
    int2*  csr    = (int2*)alloc((size_t)E * 8);
    float* h0     = (float*)alloc((size_t)n * 128 * 4);  // xW1, later reused as agg2
    float* hb     = (float*)alloc((size_t)n * 128 * 4);  // relu'd hidden
    float* agg2   = h0;

    float* outm = (float*)d_out;
    float* outl = outm + (size_t)n * 64;

    zero_kernel<<<(2 * n + THREADS - 1) / THREADS, THREADS, 0, stream>>>(deg, 2 * n);
    deg_count_kernel<<<(E + THREADS - 1) / THREADS, THREADS, 0, stream>>>(ei, ew, deg, counts, E);
    scan_part1<<<nb_scan, THREADS, 0, stream>>>(counts, deg, dinvv, partials, n);
    scan_part2<<<1, 1024, 0, stream>>>(partials, nb_scan);
    scan_part3<<<nb_scan, THREADS, 0, stream>>>(counts, partials, offs, cursor, n);
    fill_kernel<<<(E + THREADS - 1) / THREADS, THREADS, 0, stream>>>(ei, ew, dinvv, cursor,
                                                                     csr, E);
    gemm1_kernel<<<(n + 63) / 64, THREADS, 0, stream>>>(x, W1, h0, n);
    spmm_kernel<<<((size_t)n * 64 + THREADS - 1) / THREADS, THREADS, 0, stream>>>(
        h0, dinvv, offs, csr, b1, hb, n, 1);
    spmm_kernel<<<((size_t)n * 64 + THREADS - 1) / THREADS, THREADS, 0, stream>>>(
        hb, dinvv, offs, csr, nullptr, agg2, n, 0);
    gemm23_kernel<<<(n + 63) / 64, THREADS, 0, stream>>>(agg2, W2, W3, b2, b3, outm, outl, n);
}

// Round 5
// 623.634 us; speedup vs baseline: 1.6733x; 1.1686x over previous
//
#include <hip/hip_runtime.h>

// GCN encoder: h = relu(A_norm @ (x@W1) + b1); mean = (A_norm@h)@W2+b2; logstd = (A_norm@h)@W3+b3
// A_norm = sym-normalized adjacency with self-loops.
// Plan: build dst-CSR in-kernel once, SpMM = wave-per-node gather (no float atomics),
// aggregation shared between layers 2/3 (scatter commutes with weight GEMM).
// R2: 3-stage parallel scan (was 195us serial -> ~10us).
// R3/R4: spmm latency-bound -> packed int2 CSR + ping-pong software pipeline (161->~100us).
// R5: deg_count was atomic-RMW-bound (WRITE_SIZE 99.6MB = 3.2M memory-side atomics):
//     single packed u64 atomic per edge: count in bits 40+, fixed-point(2^-32) weight sum
//     in bits 0..39; returned old>>40 = edge rank -> fill_kernel needs NO atomics.
//     Total scattered atomics 4.8M -> 1.6M.

#define THREADS 256
#define SCAN_CHUNK 2048   // elements per block in the scan kernels (256 thr x 8)
#define D 4               // spmm pipeline group size (2 groups in flight = 8 feat loads)

#define DEG_MASK ((1ULL << 40) - 1)
#define CNT_SHIFT 40

// ---------------- zero init (ws is poisoned 0xAA every launch) ----------------
__global__ __launch_bounds__(THREADS) void zero_kernel(float* __restrict__ p, int n) {
    int i = blockIdx.x * THREADS + threadIdx.x;
    if (i < n) p[i] = 0.0f;   // bit pattern 0 also valid for u64 packed counters
}

// ---------------- fused histogram: one u64 atomic per edge, returns rank ----------------
__global__ __launch_bounds__(THREADS) void deg_count_kernel(
    const int* __restrict__ ei, const float* __restrict__ ew,
    unsigned long long* __restrict__ deg_cnt, int* __restrict__ rank, int E) {
    int e = blockIdx.x * THREADS + threadIdx.x;
    if (e >= E) return;
    int d = ei[E + e];                 // dst row of edge_index
    float w = ew[e];
    unsigned long long q = (unsigned long long)(w * 4294967296.0f);  // w in [0,1) -> 33 bits
    unsigned long long old = atomicAdd(&deg_cnt[d], (1ULL << CNT_SHIFT) | q);
    rank[e] = (int)(old >> CNT_SHIFT); // # prior edges to this dst = slot within CSR row
}

// ---------------- parallel scan stage 1: block sums + dinv ----------------
__global__ __launch_bounds__(THREADS) void scan_part1(
    const unsigned long long* __restrict__ deg_cnt,
    float* __restrict__ dinvv, int* __restrict__ partials, int n) {
    int t = threadIdx.x;
    int base = blockIdx.x * SCAN_CHUNK + t * 8;
    int s = 0;
#pragma unroll
    for (int i = 0; i < 8; ++i) {
        int idx = base + i;
        if (idx < n) {
            unsigned long long v = deg_cnt[idx];
            s += (int)(v >> CNT_SHIFT);
            float dg = (float)(v & DEG_MASK) * 0x1p-32f;   // un-fixed-point the weight sum
            dinvv[idx] = rsqrtf(dg + 1.0f);                // +1 = self-loop weight
        }
    }
    __shared__ int sm[THREADS];
    sm[t] = s;
    __syncthreads();
    for (int off = THREADS / 2; off > 0; off >>= 1) {
        if (t < off) sm[t] += sm[t + off];
        __syncthreads();
    }
    if (t == 0) partials[blockIdx.x] = sm[0];
}

// ---------------- parallel scan stage 2: exclusive scan of block partials ----------------
__global__ __launch_bounds__(1024) void scan_part2(int* __restrict__ partials, int nb) {
    __shared__ int s[1024];
    int t = threadIdx.x;
    int v = (t < nb) ? partials[t] : 0;
    s[t] = v;
    __syncthreads();
    for (int off = 1; off < 1024; off <<= 1) {
        int x = (t >= off) ? s[t - off] : 0;
        __syncthreads();
        s[t] += x;
        __syncthreads();
    }
    if (t < nb) partials[t] = s[t] - v;   // exclusive prefix
}

// ---------------- parallel scan stage 3: per-block local scan -> offs ----------------
__global__ __launch_bounds__(THREADS) void scan_part3(
    const unsigned long long* __restrict__ deg_cnt, const int* __restrict__ partials,
    int* __restrict__ offs, int n) {
    int t = threadIdx.x;
    int base = blockIdx.x * SCAN_CHUNK + t * 8;
    int loc[8];
    int s = 0;
#pragma unroll
    for (int i = 0; i < 8; ++i) {
        int idx = base + i;
        int c = (idx < n) ? (int)(deg_cnt[idx] >> CNT_SHIFT) : 0;
        loc[i] = c;
        s += c;
    }
    __shared__ int sm[THREADS];
    sm[t] = s;
    __syncthreads();
    for (int off = 1; off < THREADS; off <<= 1) {
        int x = (t >= off) ? sm[t - off] : 0;
        __syncthreads();
        sm[t] += x;
        __syncthreads();
    }
    int run = partials[blockIdx.x] + sm[t] - s;   // exclusive prefix of this thread's range
#pragma unroll
    for (int i = 0; i < 8; ++i) {
        int idx = base + i;
        if (idx < n) {
            offs[idx] = run;
            run += loc[i];
            if (idx == n - 1) offs[n] = run;
        }
    }
}

// ---------------- fill CSR: atomic-free (pos = offs[dst] + rank) ----------------
__global__ __launch_bounds__(THREADS) void fill_kernel(
    const int* __restrict__ ei, const float* __restrict__ ew,
    const float* __restrict__ dinvv, const int* __restrict__ offs,
    const int* __restrict__ rank, int2* __restrict__ csr, int E) {
    int e = blockIdx.x * THREADS + threadIdx.x;
    if (e >= E) return;
    int s = ei[e], d = ei[E + e];
    int pos = offs[d] + rank[e];
    csr[pos] = make_int2(s, __float_as_int(dinvv[s] * ew[e] * dinvv[d]));
}

// ---------------- GEMM1: h0[M,128] = x[M,512] @ W1[512,128], fp32 tiled ----------------
// BM=64, BN=128, BK=16; 256 threads; 4x8 micro-tile per thread.
__global__ __launch_bounds__(THREADS) void gemm1_kernel(
    const float* __restrict__ A, const float* __restrict__ B,
    float* __restrict__ C, int M) {
    __shared__ float As[16][68];    // transposed [k][m], pad 68 -> 2-way-max conflicts
    __shared__ float Bs[16][128];
    int t = threadIdx.x;
    int ty = t >> 4, tx = t & 15;
    int brow0 = blockIdx.x * 64;
    int arow = t >> 2, aq = t & 3;          // A loader: 64 rows x 4 float4
    int bkr = t >> 5, bcol = (t & 31) * 4;  // B loader: 8 rows/pass x 32 float4
    float acc[4][8];
#pragma unroll
    for (int i = 0; i < 4; i++)
#pragma unroll
        for (int j = 0; j < 8; j++) acc[i][j] = 0.0f;
    int gr = brow0 + arow;
    const float4 z4 = make_float4(0.f, 0.f, 0.f, 0.f);
    for (int k0 = 0; k0 < 512; k0 += 16) {
        float4 av = (gr < M) ? *(const float4*)&A[(size_t)gr * 512 + k0 + aq * 4] : z4;
        float4 b0 = *(const float4*)&B[(size_t)(k0 + bkr) * 128 + bcol];
        float4 b1 = *(const float4*)&B[(size_t)(k0 + bkr + 8) * 128 + bcol];
        __syncthreads();
        As[aq * 4 + 0][arow] = av.x;
        As[aq * 4 + 1][arow] = av.y;
        As[aq * 4 + 2][arow] = av.z;
        As[aq * 4 + 3][arow] = av.w;
        *(float4*)&Bs[bkr][bcol] = b0;
        *(float4*)&Bs[bkr + 8][bcol] = b1;
        __syncthreads();
#pragma unroll
        for (int kk = 0; kk < 16; ++kk) {
            float4 a = *(const float4*)&As[kk][ty * 4];
            float4 p0 = *(const float4*)&Bs[kk][tx * 8];
            float4 p1 = *(const float4*)&Bs[kk][tx * 8 + 4];
            float av_[4] = {a.x, a.y, a.z, a.w};
            float bv_[8] = {p0.x, p0.y, p0.z, p0.w, p1.x, p1.y, p1.z, p1.w};
#pragma unroll
            for (int i = 0; i < 4; i++)
#pragma unroll
                for (int j = 0; j < 8; j++)
                    acc[i][j] = fmaf(av_[i], bv_[j], acc[i][j]);
        }
    }
#pragma unroll
    for (int i = 0; i < 4; i++) {
        int r = brow0 + ty * 4 + i;
        if (r < M) {
            *(float4*)&C[(size_t)r * 128 + tx * 8] =
                make_float4(acc[i][0], acc[i][1], acc[i][2], acc[i][3]);
            *(float4*)&C[(size_t)r * 128 + tx * 8 + 4] =
                make_float4(acc[i][4], acc[i][5], acc[i][6], acc[i][7]);
        }
    }
}

// ---------------- SpMM: out[d,:] = sum_e w_e * feat[src_e,:] + dinv[d]^2 * feat[d,:] ----
// one wave per dst node; 2 channels per lane (float2); software-pipelined gather:
//   csr loads are scalar (readfirstlane'd dst -> uniform addr -> s_load, lgkmcnt)
//   feat loads ping-pong, 2 groups of D in flight on vmcnt.
__global__ __launch_bounds__(THREADS) void spmm_kernel(
    const float* __restrict__ feat, const float* __restrict__ dinvv,
    const int* __restrict__ offs, const int2* __restrict__ csr,
    const float* __restrict__ bias, float* __restrict__ out, int n, int do_relu) {
    int gw = (blockIdx.x * THREADS + threadIdx.x) >> 6;
    int lane = threadIdx.x & 63;
    if (gw >= n) return;
    const int d = __builtin_amdgcn_readfirstlane(gw);   // wave-uniform -> SALU/s_load path
    float di = dinvv[d];
    float sw = di * di;                       // self-loop norm = 1/deg
    const float2* __restrict__ f2 = (const float2*)feat + lane;   // f2[64*row]
    float2 acc = f2[(size_t)d * 64];
    acc.x *= sw;
    acc.y *= sw;
    int j0 = offs[d];
    int m = offs[d + 1] - j0;
    const int2* __restrict__ cp = csr + j0;

    int2 eA[D], eB[D];
    float wA[D], wB[D];
    float2 vA[D], vB[D];

    // prologue: csr groups 0 and 1; feat group 0 in flight
#pragma unroll
    for (int i = 0; i < D; ++i) if (i < m) eA[i] = cp[i];
#pragma unroll
    for (int i = 0; i < D; ++i) if (D + i < m) eB[i] = cp[D + i];
#pragma unroll
    for (int i = 0; i < D; ++i) if (i < m) {
        wA[i] = __int_as_float(eA[i].y);
        vA[i] = f2[(size_t)eA[i].x * 64];
    }

    int g = 0;
    for (; g + 4 * D <= m; g += 2 * D) {
        // half 1: consume group g (vA/wA); eB holds csr(g+D)
#pragma unroll
        for (int i = 0; i < D; ++i) eA[i] = cp[g + 2 * D + i];       // csr for g+2D
#pragma unroll
        for (int i = 0; i < D; ++i) {
            wB[i] = __int_as_float(eB[i].y);
            vB[i] = f2[(size_t)eB[i].x * 64];                        // feat for g+D
        }
#pragma unroll
        for (int i = 0; i < D; ++i) {
            acc.x = fmaf(wA[i], vA[i].x, acc.x);
            acc.y = fmaf(wA[i], vA[i].y, acc.y);
        }
        // half 2: consume group g+D (vB/wB); eA holds csr(g+2D)
#pragma unroll
        for (int i = 0; i < D; ++i) eB[i] = cp[g + 3 * D + i];       // csr for g+3D
#pragma unroll
        for (int i = 0; i < D; ++i) {
            wA[i] = __int_as_float(eA[i].y);
            vA[i] = f2[(size_t)eA[i].x * 64];                        // feat for g+2D
        }
#pragma unroll
        for (int i = 0; i < D; ++i) {
            acc.x = fmaf(wB[i], vB[i].x, acc.x);
            acc.y = fmaf(wB[i], vB[i].y, acc.y);
        }
    }
    // epilogue: group g in flight (vA), csr for group g+D resident in eB (guarded)
#pragma unroll
    for (int i = 0; i < D; ++i) if (g + i < m) {
        acc.x = fmaf(wA[i], vA[i].x, acc.x);
        acc.y = fmaf(wA[i], vA[i].y, acc.y);
    }
    g += D;
#pragma unroll
    for (int i = 0; i < D; ++i) if (g + i < m) {
        float w = __int_as_float(eB[i].y);
        float2 v = f2[(size_t)eB[i].x * 64];
        acc.x = fmaf(w, v.x, acc.x);
        acc.y = fmaf(w, v.y, acc.y);
    }
    g += D;
    for (; g < m; ++g) {
        int2 e = cp[g];
        float w = __int_as_float(e.y);
        float2 v = f2[(size_t)e.x * 64];
        acc.x = fmaf(w, v.x, acc.x);
        acc.y = fmaf(w, v.y, acc.y);
    }

    if (bias) {
        float2 b = *(const float2*)&bias[lane * 2];
        acc.x += b.x;
        acc.y += b.y;
    }
    if (do_relu) {
        acc.x = fmaxf(acc.x, 0.0f);
        acc.y = fmaxf(acc.y, 0.0f);
    }
    ((float2*)out)[(size_t)d * 64 + lane] = acc;
}

// ---------------- GEMM23: [mean|logstd] = agg2[M,128] @ [W2|W3][128,128] + [b2|b3] ------
__global__ __launch_bounds__(THREADS) void gemm23_kernel(
    const float* __restrict__ A, const float* __restrict__ W2,
    const float* __restrict__ W3, const float* __restrict__ b2,
    const float* __restrict__ b3, float* __restrict__ outm,
    float* __restrict__ outl, int M) {
    __shared__ float As[16][68];
    __shared__ float Bs[16][128];
    int t = threadIdx.x;
    int ty = t >> 4, tx = t & 15;
    int brow0 = blockIdx.x * 64;
    int arow = t >> 2, aq = t & 3;
    int bkr = t >> 5, bcol = (t & 31) * 4;
    float acc[4][8];
#pragma unroll
    for (int i = 0; i < 4; i++)
#pragma unroll
        for (int j = 0; j < 8; j++) acc[i][j] = 0.0f;
    int gr = brow0 + arow;
    const float4 z4 = make_float4(0.f, 0.f, 0.f, 0.f);
    for (int k0 = 0; k0 < 128; k0 += 16) {
        float4 av = (gr < M) ? *(const float4*)&A[(size_t)gr * 128 + k0 + aq * 4] : z4;
        int k1 = k0 + bkr, k2 = k0 + bkr + 8;
        float4 b0 = (bcol < 64) ? *(const float4*)&W2[(size_t)k1 * 64 + bcol]
                                : *(const float4*)&W3[(size_t)k1 * 64 + bcol - 64];
        float4 b1 = (bcol < 64) ? *(const float4*)&W2[(size_t)k2 * 64 + bcol]
                                : *(const float4*)&W3[(size_t)k2 * 64 + bcol - 64];
        __syncthreads();
        As[aq * 4 + 0][arow] = av.x;
        As[aq * 4 + 1][arow] = av.y;
        As[aq * 4 + 2][arow] = av.z;
        As[aq * 4 + 3][arow] = av.w;
        *(float4*)&Bs[bkr][bcol] = b0;
        *(float4*)&Bs[bkr + 8][bcol] = b1;
        __syncthreads();
#pragma unroll
        for (int kk = 0; kk < 16; ++kk) {
            float4 a = *(const float4*)&As[kk][ty * 4];
            float4 p0 = *(const float4*)&Bs[kk][tx * 8];
            float4 p1 = *(const float4*)&Bs[kk][tx * 8 + 4];
            float av_[4] = {a.x, a.y, a.z, a.w};
            float bv_[8] = {p0.x, p0.y, p0.z, p0.w, p1.x, p1.y, p1.z, p1.w};
#pragma unroll
            for (int i = 0; i < 4; i++)
#pragma unroll
                for (int j = 0; j < 8; j++)
                    acc[i][j] = fmaf(av_[i], bv_[j], acc[i][j]);
        }
    }
    // epilogue: cols 0..63 -> mean (+b2), 64..127 -> logstd (+b3)
    bool is_mean = (tx < 8);
    int c = is_mean ? tx * 8 : tx * 8 - 64;
    const float* bb = is_mean ? b2 : b3;
    float* op = is_mean ? outm : outl;
    float4 bias0 = *(const float4*)&bb[c];
    float4 bias1 = *(const float4*)&bb[c + 4];
#pragma unroll
    for (int i = 0; i < 4; i++) {
        int r = brow0 + ty * 4 + i;
        if (r < M) {
            *(float4*)&op[(size_t)r * 64 + c] =
                make_float4(acc[i][0] + bias0.x, acc[i][1] + bias0.y,
                            acc[i][2] + bias0.z, acc[i][3] + bias0.w);
            *(float4*)&op[(size_t)r * 64 + c + 4] =
                make_float4(acc[i][4] + bias1.x, acc[i][5] + bias1.y,
                            acc[i][6] + bias1.z, acc[i][7] + bias1.w);
        }
    }
}

extern "C" void kernel_launch(void* const* d_in, const int* in_sizes, int n_in,
                              void* d_out, int out_size, void* d_ws, size_t ws_size,
                              hipStream_t stream) {
    const float* x  = (const float*)d_in[0];
    const int*   ei = (const int*)d_in[1];
    const float* ew = (const float*)d_in[2];
    const float* W1 = (const float*)d_in[3];
    const float* b1 = (const float*)d_in[4];
    const float* W2 = (const float*)d_in[5];
    const float* b2 = (const float*)d_in[6];
    const float* W3 = (const float*)d_in[7];
    const float* b3 = (const float*)d_in[8];

    const int n = in_sizes[0] / 512;   // 50000
    const int E = in_sizes[2];         // 1600000
    const int nb_scan = (n + SCAN_CHUNK - 1) / SCAN_CHUNK;   // 25

    // workspace carve-up (512B-aligned chunks), ~72 MB total
    char* p = (char*)d_ws;
    auto alloc = [&](size_t bytes) {
        char* q = p;
        p += (bytes + 511) & ~(size_t)511;
        return q;
    };
    unsigned long long* deg_cnt = (unsigned long long*)alloc((size_t)n * 8);
    float* dinvv  = (float*)alloc((size_t)n * 4);
    int*   offs   = (int*)alloc((size_t)(n + 1) * 4);
    int*   rank   = (int*)alloc((size_t)E * 4);
    int*   partials = (int*)alloc((size_t)nb_scan * 4);
    int2*  csr    = (int2*)alloc((size_t)E * 8);
    float* h0     = (float*)alloc((size_t)n * 128 * 4);  // xW1, later reused as agg2
    float* hb     = (float*)alloc((size_t)n * 128 * 4);  // relu'd hidden
    float* agg2   = h0;

    float* outm = (float*)d_out;
    float* outl = outm + (size_t)n * 64;

    zero_kernel<<<(2 * n + THREADS - 1) / THREADS, THREADS, 0, stream>>>((float*)deg_cnt, 2 * n);
    deg_count_kernel<<<(E + THREADS - 1) / THREADS, THREADS, 0, stream>>>(ei, ew, deg_cnt, rank, E);
    scan_part1<<<nb_scan, THREADS, 0, stream>>>(deg_cnt, dinvv, partials, n);
    scan_part2<<<1, 1024, 0, stream>>>(partials, nb_scan);
    scan_part3<<<nb_scan, THREADS, 0, stream>>>(deg_cnt, partials, offs, n);
    fill_kernel<<<(E + THREADS - 1) / THREADS, THREADS, 0, stream>>>(ei, ew, dinvv, offs,
                                                                     rank, csr, E);
    gemm1_kernel<<<(n + 63) / 64, THREADS, 0, stream>>>(x, W1, h0, n);
    spmm_kernel<<<((size_t)n * 64 + THREADS - 1) / THREADS, THREADS, 0, stream>>>(
        h0, dinvv, offs, csr, b1, hb, n, 1);
    spmm_kernel<<<((size_t)n * 64 + THREADS - 1) / THREADS, THREADS, 0, stream>>>(
        hb, dinvv, offs, csr, nullptr, agg2, n, 0);
    gemm23_kernel<<<(n + 63) / 64, THREADS, 0, stream>>>(agg2, W2, W3, b2, b3, outm, outl, n);
}

// Round 6
// 577.676 us; speedup vs baseline: 1.8064x; 1.0796x over previous
//
#include <hip/hip_runtime.h>

// GCN encoder: h = relu(A_norm @ (x@W1) + b1); mean = (A_norm@h)@W2+b2; logstd = (A_norm@h)@W3+b3
// A_norm = sym-normalized adjacency with self-loops.
// R2: 3-stage parallel scan. R3/R4: spmm ping-pong software pipeline (161->~100us).
// R5: one packed u64 atomic per edge (count<<40 | fixpoint weight sum), rank from return
//     value -> atomic-free fill. R6: gemm1 was VALU-bound fp32 (38% VALU, 0 MFMA, 129us):
//     split-bf16 MFMA GEMM (f32 = hi+lo bf16; 3 MFMA products, err ~2^-17) -> matrix pipe.

#define THREADS 256
#define SCAN_CHUNK 2048   // elements per block in the scan kernels (256 thr x 8)
#define D 4               // spmm pipeline group size (2 groups in flight = 8 feat loads)

#define DEG_MASK ((1ULL << 40) - 1)
#define CNT_SHIFT 40

typedef __attribute__((ext_vector_type(8))) short short8;   // 8 bf16 (4 VGPRs)
typedef __attribute__((ext_vector_type(4))) float floatx4;  // MFMA acc

// ---------------- zero init (ws is poisoned 0xAA every launch) ----------------
__global__ __launch_bounds__(THREADS) void zero_kernel(float* __restrict__ p, int n) {
    int i = blockIdx.x * THREADS + threadIdx.x;
    if (i < n) p[i] = 0.0f;   // bit pattern 0 also valid for u64 packed counters
}

// ---------------- fused histogram: one u64 atomic per edge, returns rank ----------------
__global__ __launch_bounds__(THREADS) void deg_count_kernel(
    const int* __restrict__ ei, const float* __restrict__ ew,
    unsigned long long* __restrict__ deg_cnt, int* __restrict__ rank, int E) {
    int e = blockIdx.x * THREADS + threadIdx.x;
    if (e >= E) return;
    int d = ei[E + e];                 // dst row of edge_index
    float w = ew[e];
    unsigned long long q = (unsigned long long)(w * 4294967296.0f);  // w in [0,1) -> 33 bits
    unsigned long long old = atomicAdd(&deg_cnt[d], (1ULL << CNT_SHIFT) | q);
    rank[e] = (int)(old >> CNT_SHIFT); // # prior edges to this dst = slot within CSR row
}

// ---------------- parallel scan stage 1: block sums + dinv ----------------
__global__ __launch_bounds__(THREADS) void scan_part1(
    const unsigned long long* __restrict__ deg_cnt,
    float* __restrict__ dinvv, int* __restrict__ partials, int n) {
    int t = threadIdx.x;
    int base = blockIdx.x * SCAN_CHUNK + t * 8;
    int s = 0;
#pragma unroll
    for (int i = 0; i < 8; ++i) {
        int idx = base + i;
        if (idx < n) {
            unsigned long long v = deg_cnt[idx];
            s += (int)(v >> CNT_SHIFT);
            float dg = (float)(v & DEG_MASK) * 0x1p-32f;   // un-fixed-point the weight sum
            dinvv[idx] = rsqrtf(dg + 1.0f);                // +1 = self-loop weight
        }
    }
    __shared__ int sm[THREADS];
    sm[t] = s;
    __syncthreads();
    for (int off = THREADS / 2; off > 0; off >>= 1) {
        if (t < off) sm[t] += sm[t + off];
        __syncthreads();
    }
    if (t == 0) partials[blockIdx.x] = sm[0];
}

// ---------------- parallel scan stage 2: exclusive scan of block partials ----------------
__global__ __launch_bounds__(1024) void scan_part2(int* __restrict__ partials, int nb) {
    __shared__ int s[1024];
    int t = threadIdx.x;
    int v = (t < nb) ? partials[t] : 0;
    s[t] = v;
    __syncthreads();
    for (int off = 1; off < 1024; off <<= 1) {
        int x = (t >= off) ? s[t - off] : 0;
        __syncthreads();
        s[t] += x;
        __syncthreads();
    }
    if (t < nb) partials[t] = s[t] - v;   // exclusive prefix
}

// ---------------- parallel scan stage 3: per-block local scan -> offs ----------------
__global__ __launch_bounds__(THREADS) void scan_part3(
    const unsigned long long* __restrict__ deg_cnt, const int* __restrict__ partials,
    int* __restrict__ offs, int n) {
    int t = threadIdx.x;
    int base = blockIdx.x * SCAN_CHUNK + t * 8;
    int loc[8];
    int s = 0;
#pragma unroll
    for (int i = 0; i < 8; ++i) {
        int idx = base + i;
        int c = (idx < n) ? (int)(deg_cnt[idx] >> CNT_SHIFT) : 0;
        loc[i] = c;
        s += c;
    }
    __shared__ int sm[THREADS];
    sm[t] = s;
    __syncthreads();
    for (int off = 1; off < THREADS; off <<= 1) {
        int x = (t >= off) ? sm[t - off] : 0;
        __syncthreads();
        sm[t] += x;
        __syncthreads();
    }
    int run = partials[blockIdx.x] + sm[t] - s;   // exclusive prefix of this thread's range
#pragma unroll
    for (int i = 0; i < 8; ++i) {
        int idx = base + i;
        if (idx < n) {
            offs[idx] = run;
            run += loc[i];
            if (idx == n - 1) offs[n] = run;
        }
    }
}

// ---------------- fill CSR: atomic-free (pos = offs[dst] + rank) ----------------
__global__ __launch_bounds__(THREADS) void fill_kernel(
    const int* __restrict__ ei, const float* __restrict__ ew,
    const float* __restrict__ dinvv, const int* __restrict__ offs,
    const int* __restrict__ rank, int2* __restrict__ csr, int E) {
    int e = blockIdx.x * THREADS + threadIdx.x;
    if (e >= E) return;
    int s = ei[e], d = ei[E + e];
    int pos = offs[d] + rank[e];
    csr[pos] = make_int2(s, __float_as_int(dinvv[s] * ew[e] * dinvv[d]));
}

// ---------------- W1 split+transpose: Wt_hi/lo[n=128][k=512] bf16 ----------------
__global__ __launch_bounds__(THREADS) void wsplit_kernel(
    const float* __restrict__ W, unsigned short* __restrict__ hi,
    unsigned short* __restrict__ lo) {
    int id = blockIdx.x * THREADS + threadIdx.x;   // 65536 = 512*128
    if (id >= 512 * 128) return;
    int k = id >> 7, n = id & 127;
    float v = W[id];                               // W[k][n]
    unsigned int b = __float_as_uint(v);
    unsigned short h = (unsigned short)(b >> 16);  // truncated hi bf16
    float fh = __uint_as_float(b & 0xFFFF0000u);
    unsigned short l = (unsigned short)(__float_as_uint(v - fh) >> 16);  // residual bf16
    hi[n * 512 + k] = h;
    lo[n * 512 + k] = l;
}

// ---------------- GEMM1 (MFMA): h0[M,128] = x[M,512] @ W1[512,128] ----------------
// Split-bf16: x = xh + xl, w = wh + wl; acc += xh*wh + xh*wl + xl*wh (err ~2^-17).
// BM=64, BN=128, BK=64; 4 waves in 2x2; per wave 32x64 = 2x4 frags of 16x16x32.
// LDS rows padded to 72 bf16 (144B = 9*16B): aligned b128 reads, 2-way (free) conflicts.
__global__ __launch_bounds__(THREADS) void gemm1_mfma_kernel(
    const float* __restrict__ A, const unsigned short* __restrict__ Wth,
    const unsigned short* __restrict__ Wtl, float* __restrict__ C, int M) {
    __shared__ unsigned short As[2][64][72];    // [hi/lo][m][k]
    __shared__ unsigned short Bs[2][128][72];   // [hi/lo][n][k]
    int t = threadIdx.x;
    int brow0 = blockIdx.x * 64;
    // staging coords
    int arow = t >> 2, akq = (t & 3) * 16;      // A: 64 rows x 4 chunks of 16 f32
    int bn = t >> 1, bkoff = (t & 1) * 32;      // B: 128 rows x 2 chunks of 32 bf16
    // compute coords
    int wid = t >> 6, lane = t & 63;
    int wr = wid >> 1, wc = wid & 1;            // 2x2 wave grid
    int lm = lane & 15, lk = (lane >> 4) * 8;
    floatx4 acc[2][4];
#pragma unroll
    for (int i = 0; i < 2; i++)
#pragma unroll
        for (int j = 0; j < 4; j++) acc[i][j] = (floatx4)0.0f;

    int gr = brow0 + arow;
    for (int k0 = 0; k0 < 512; k0 += 64) {
        __syncthreads();
        // ---- stage A tile: read f32, split into hi/lo bf16 planes ----
        {
            const float* ap = &A[(size_t)gr * 512 + k0 + akq];
#pragma unroll
            for (int i = 0; i < 4; ++i) {
                float4 v = (gr < M) ? *(const float4*)&ap[i * 4]
                                    : make_float4(0.f, 0.f, 0.f, 0.f);
                float e[4] = {v.x, v.y, v.z, v.w};
                ushort4 h4, l4;
                unsigned short* hp = (unsigned short*)&h4;
                unsigned short* lp = (unsigned short*)&l4;
#pragma unroll
                for (int c = 0; c < 4; ++c) {
                    unsigned int b = __float_as_uint(e[c]);
                    hp[c] = (unsigned short)(b >> 16);
                    float fh = __uint_as_float(b & 0xFFFF0000u);
                    lp[c] = (unsigned short)(__float_as_uint(e[c] - fh) >> 16);
                }
                *(ushort4*)&As[0][arow][akq + i * 4] = h4;
                *(ushort4*)&As[1][arow][akq + i * 4] = l4;
            }
        }
        // ---- stage B tile: straight copy from pre-split transposed W ----
        {
            const unsigned short* bh = &Wth[(size_t)bn * 512 + k0 + bkoff];
            const unsigned short* bl = &Wtl[(size_t)bn * 512 + k0 + bkoff];
#pragma unroll
            for (int s = 0; s < 4; ++s) {
                *(float4*)&Bs[0][bn][bkoff + s * 8] = *(const float4*)&bh[s * 8];
                *(float4*)&Bs[1][bn][bkoff + s * 8] = *(const float4*)&bl[s * 8];
            }
        }
        __syncthreads();
        // ---- MFMA: 2 k-chunks x (2 m-frags x 4 n-frags) x 3 hi/lo products ----
#pragma unroll
        for (int kc = 0; kc < 2; ++kc) {
            int kb = kc * 32 + lk;
            short8 ah[2], al[2], bh[4], bl[4];
#pragma unroll
            for (int mf = 0; mf < 2; ++mf) {
                ah[mf] = *(const short8*)&As[0][wr * 32 + mf * 16 + lm][kb];
                al[mf] = *(const short8*)&As[1][wr * 32 + mf * 16 + lm][kb];
            }
#pragma unroll
            for (int nf = 0; nf < 4; ++nf) {
                bh[nf] = *(const short8*)&Bs[0][wc * 64 + nf * 16 + lm][kb];
                bl[nf] = *(const short8*)&Bs[1][wc * 64 + nf * 16 + lm][kb];
            }
#pragma unroll
            for (int mf = 0; mf < 2; ++mf)
#pragma unroll
                for (int nf = 0; nf < 4; ++nf) {
                    acc[mf][nf] = __builtin_amdgcn_mfma_f32_16x16x32_bf16(
                        ah[mf], bh[nf], acc[mf][nf], 0, 0, 0);
                    acc[mf][nf] = __builtin_amdgcn_mfma_f32_16x16x32_bf16(
                        ah[mf], bl[nf], acc[mf][nf], 0, 0, 0);
                    acc[mf][nf] = __builtin_amdgcn_mfma_f32_16x16x32_bf16(
                        al[mf], bh[nf], acc[mf][nf], 0, 0, 0);
                }
        }
    }
    // ---- epilogue: C/D layout col = lane&15, row = (lane>>4)*4 + reg ----
#pragma unroll
    for (int mf = 0; mf < 2; ++mf) {
        int rbase = brow0 + wr * 32 + mf * 16 + (lane >> 4) * 4;
#pragma unroll
        for (int nf = 0; nf < 4; ++nf) {
            int col = wc * 64 + nf * 16 + lm;
#pragma unroll
            for (int r = 0; r < 4; ++r) {
                int g = rbase + r;
                if (g < M) C[(size_t)g * 128 + col] = acc[mf][nf][r];
            }
        }
    }
}

// ---------------- SpMM: out[d,:] = sum_e w_e * feat[src_e,:] + dinv[d]^2 * feat[d,:] ----
// one wave per dst node; 2 channels per lane (float2); software-pipelined gather:
//   csr loads are scalar (readfirstlane'd dst -> uniform addr -> s_load, lgkmcnt)
//   feat loads ping-pong, 2 groups of D in flight on vmcnt.
__global__ __launch_bounds__(THREADS) void spmm_kernel(
    const float* __restrict__ feat, const float* __restrict__ dinvv,
    const int* __restrict__ offs, const int2* __restrict__ csr,
    const float* __restrict__ bias, float* __restrict__ out, int n, int do_relu) {
    int gw = (blockIdx.x * THREADS + threadIdx.x) >> 6;
    int lane = threadIdx.x & 63;
    if (gw >= n) return;
    const int d = __builtin_amdgcn_readfirstlane(gw);   // wave-uniform -> SALU/s_load path
    float di = dinvv[d];
    float sw = di * di;                       // self-loop norm = 1/deg
    const float2* __restrict__ f2 = (const float2*)feat + lane;   // f2[64*row]
    float2 acc = f2[(size_t)d * 64];
    acc.x *= sw;
    acc.y *= sw;
    int j0 = offs[d];
    int m = offs[d + 1] - j0;
    const int2* __restrict__ cp = csr + j0;

    int2 eA[D], eB[D];
    float wA[D], wB[D];
    float2 vA[D], vB[D];

    // prologue: csr groups 0 and 1; feat group 0 in flight
#pragma unroll
    for (int i = 0; i < D; ++i) if (i < m) eA[i] = cp[i];
#pragma unroll
    for (int i = 0; i < D; ++i) if (D + i < m) eB[i] = cp[D + i];
#pragma unroll
    for (int i = 0; i < D; ++i) if (i < m) {
        wA[i] = __int_as_float(eA[i].y);
        vA[i] = f2[(size_t)eA[i].x * 64];
    }

    int g = 0;
    for (; g + 4 * D <= m; g += 2 * D) {
        // half 1: consume group g (vA/wA); eB holds csr(g+D)
#pragma unroll
        for (int i = 0; i < D; ++i) eA[i] = cp[g + 2 * D + i];       // csr for g+2D
#pragma unroll
        for (int i = 0; i < D; ++i) {
            wB[i] = __int_as_float(eB[i].y);
            vB[i] = f2[(size_t)eB[i].x * 64];                        // feat for g+D
        }
#pragma unroll
        for (int i = 0; i < D; ++i) {
            acc.x = fmaf(wA[i], vA[i].x, acc.x);
            acc.y = fmaf(wA[i], vA[i].y, acc.y);
        }
        // half 2: consume group g+D (vB/wB); eA holds csr(g+2D)
#pragma unroll
        for (int i = 0; i < D; ++i) eB[i] = cp[g + 3 * D + i];       // csr for g+3D
#pragma unroll
        for (int i = 0; i < D; ++i) {
            wA[i] = __int_as_float(eA[i].y);
            vA[i] = f2[(size_t)eA[i].x * 64];                        // feat for g+2D
        }
#pragma unroll
        for (int i = 0; i < D; ++i) {
            acc.x = fmaf(wB[i], vB[i].x, acc.x);
            acc.y = fmaf(wB[i], vB[i].y, acc.y);
        }
    }
    // epilogue: group g in flight (vA), csr for group g+D resident in eB (guarded)
#pragma unroll
    for (int i = 0; i < D; ++i) if (g + i < m) {
        acc.x = fmaf(wA[i], vA[i].x, acc.x);
        acc.y = fmaf(wA[i], vA[i].y, acc.y);
    }
    g += D;
#pragma unroll
    for (int i = 0; i < D; ++i) if (g + i < m) {
        float w = __int_as_float(eB[i].y);
        float2 v = f2[(size_t)eB[i].x * 64];
        acc.x = fmaf(w, v.x, acc.x);
        acc.y = fmaf(w, v.y, acc.y);
    }
    g += D;
    for (; g < m; ++g) {
        int2 e = cp[g];
        float w = __int_as_float(e.y);
        float2 v = f2[(size_t)e.x * 64];
        acc.x = fmaf(w, v.x, acc.x);
        acc.y = fmaf(w, v.y, acc.y);
    }

    if (bias) {
        float2 b = *(const float2*)&bias[lane * 2];
        acc.x += b.x;
        acc.y += b.y;
    }
    if (do_relu) {
        acc.x = fmaxf(acc.x, 0.0f);
        acc.y = fmaxf(acc.y, 0.0f);
    }
    ((float2*)out)[(size_t)d * 64 + lane] = acc;
}

// ---------------- GEMM23: [mean|logstd] = agg2[M,128] @ [W2|W3][128,128] + [b2|b3] ------
__global__ __launch_bounds__(THREADS) void gemm23_kernel(
    const float* __restrict__ A, const float* __restrict__ W2,
    const float* __restrict__ W3, const float* __restrict__ b2,
    const float* __restrict__ b3, float* __restrict__ outm,
    float* __restrict__ outl, int M) {
    __shared__ float As[16][68];
    __shared__ float Bs[16][128];
    int t = threadIdx.x;
    int ty = t >> 4, tx = t & 15;
    int brow0 = blockIdx.x * 64;
    int arow = t >> 2, aq = t & 3;
    int bkr = t >> 5, bcol = (t & 31) * 4;
    float acc[4][8];
#pragma unroll
    for (int i = 0; i < 4; i++)
#pragma unroll
        for (int j = 0; j < 8; j++) acc[i][j] = 0.0f;
    int gr = brow0 + arow;
    const float4 z4 = make_float4(0.f, 0.f, 0.f, 0.f);
    for (int k0 = 0; k0 < 128; k0 += 16) {
        float4 av = (gr < M) ? *(const float4*)&A[(size_t)gr * 128 + k0 + aq * 4] : z4;
        int k1 = k0 + bkr, k2 = k0 + bkr + 8;
        float4 b0 = (bcol < 64) ? *(const float4*)&W2[(size_t)k1 * 64 + bcol]
                                : *(const float4*)&W3[(size_t)k1 * 64 + bcol - 64];
        float4 b1 = (bcol < 64) ? *(const float4*)&W2[(size_t)k2 * 64 + bcol]
                                : *(const float4*)&W3[(size_t)k2 * 64 + bcol - 64];
        __syncthreads();
        As[aq * 4 + 0][arow] = av.x;
        As[aq * 4 + 1][arow] = av.y;
        As[aq * 4 + 2][arow] = av.z;
        As[aq * 4 + 3][arow] = av.w;
        *(float4*)&Bs[bkr][bcol] = b0;
        *(float4*)&Bs[bkr + 8][bcol] = b1;
        __syncthreads();
#pragma unroll
        for (int kk = 0; kk < 16; ++kk) {
            float4 a = *(const float4*)&As[kk][ty * 4];
            float4 p0 = *(const float4*)&Bs[kk][tx * 8];
            float4 p1 = *(const float4*)&Bs[kk][tx * 8 + 4];
            float av_[4] = {a.x, a.y, a.z, a.w};
            float bv_[8] = {p0.x, p0.y, p0.z, p0.w, p1.x, p1.y, p1.z, p1.w};
#pragma unroll
            for (int i = 0; i < 4; i++)
#pragma unroll
                for (int j = 0; j < 8; j++)
                    acc[i][j] = fmaf(av_[i], bv_[j], acc[i][j]);
        }
    }
    // epilogue: cols 0..63 -> mean (+b2), 64..127 -> logstd (+b3)
    bool is_mean = (tx < 8);
    int c = is_mean ? tx * 8 : tx * 8 - 64;
    const float* bb = is_mean ? b2 : b3;
    float* op = is_mean ? outm : outl;
    float4 bias0 = *(const float4*)&bb[c];
    float4 bias1 = *(const float4*)&bb[c + 4];
#pragma unroll
    for (int i = 0; i < 4; i++) {
        int r = brow0 + ty * 4 + i;
        if (r < M) {
            *(float4*)&op[(size_t)r * 64 + c] =
                make_float4(acc[i][0] + bias0.x, acc[i][1] + bias0.y,
                            acc[i][2] + bias0.z, acc[i][3] + bias0.w);
            *(float4*)&op[(size_t)r * 64 + c + 4] =
                make_float4(acc[i][4] + bias1.x, acc[i][5] + bias1.y,
                            acc[i][6] + bias1.z, acc[i][7] + bias1.w);
        }
    }
}

extern "C" void kernel_launch(void* const* d_in, const int* in_sizes, int n_in,
                              void* d_out, int out_size, void* d_ws, size_t ws_size,
                              hipStream_t stream) {
    const float* x  = (const float*)d_in[0];
    const int*   ei = (const int*)d_in[1];
    const float* ew = (const float*)d_in[2];
    const float* W1 = (const float*)d_in[3];
    const float* b1 = (const float*)d_in[4];
    const float* W2 = (const float*)d_in[5];
    const float* b2 = (const float*)d_in[6];
    const float* W3 = (const float*)d_in[7];
    const float* b3 = (const float*)d_in[8];

    const int n = in_sizes[0] / 512;   // 50000
    const int E = in_sizes[2];         // 1600000
    const int nb_scan = (n + SCAN_CHUNK - 1) / SCAN_CHUNK;   // 25

    // workspace carve-up (512B-aligned chunks), ~72 MB total
    char* p = (char*)d_ws;
    auto alloc = [&](size_t bytes) {
        char* q = p;
        p += (bytes + 511) & ~(size_t)511;
        return q;
    };
    unsigned long long* deg_cnt = (unsigned long long*)alloc((size_t)n * 8);
    float* dinvv  = (float*)alloc((size_t)n * 4);
    int*   offs   = (int*)alloc((size_t)(n + 1) * 4);
    int*   rank   = (int*)alloc((size_t)E * 4);
    int*   partials = (int*)alloc((size_t)nb_scan * 4);
    int2*  csr    = (int2*)alloc((size_t)E * 8);
    unsigned short* Wth = (unsigned short*)alloc((size_t)512 * 128 * 2);
    unsigned short* Wtl = (unsigned short*)alloc((size_t)512 * 128 * 2);
    float* h0     = (float*)alloc((size_t)n * 128 * 4);  // xW1, later reused as agg2
    float* hb     = (float*)alloc((size_t)n * 128 * 4);  // relu'd hidden
    float* agg2   = h0;

    float* outm = (float*)d_out;
    float* outl = outm + (size_t)n * 64;

    zero_kernel<<<(2 * n + THREADS - 1) / THREADS, THREADS, 0, stream>>>((float*)deg_cnt, 2 * n);
    deg_count_kernel<<<(E + THREADS - 1) / THREADS, THREADS, 0, stream>>>(ei, ew, deg_cnt, rank, E);
    scan_part1<<<nb_scan, THREADS, 0, stream>>>(deg_cnt, dinvv, partials, n);
    scan_part2<<<1, 1024, 0, stream>>>(partials, nb_scan);
    scan_part3<<<nb_scan, THREADS, 0, stream>>>(deg_cnt, partials, offs, n);
    fill_kernel<<<(E + THREADS - 1) / THREADS, THREADS, 0, stream>>>(ei, ew, dinvv, offs,
                                                                     rank, csr, E);
    wsplit_kernel<<<(512 * 128 + THREADS - 1) / THREADS, THREADS, 0, stream>>>(W1, Wth, Wtl);
    gemm1_mfma_kernel<<<(n + 63) / 64, THREADS, 0, stream>>>(x, Wth, Wtl, h0, n);
    spmm_kernel<<<((size_t)n * 64 + THREADS - 1) / THREADS, THREADS, 0, stream>>>(
        h0, dinvv, offs, csr, b1, hb, n, 1);
    spmm_kernel<<<((size_t)n * 64 + THREADS - 1) / THREADS, THREADS, 0, stream>>>(
        hb, dinvv, offs, csr, nullptr, agg2, n, 0);
    gemm23_kernel<<<(n + 63) / 64, THREADS, 0, stream>>>(agg2, W2, W3, b2, b3, outm, outl, n);
}